// Round 13
// baseline (200.345 us; speedup 1.0000x reference)
//
#include <hip/hip_runtime.h>
#include <hip/hip_bf16.h>

#define HH  56
#define WWC 56
#define HWP 3136   // 56*56 = 49*64
#define CC  256
#define NSPLIT 4

typedef unsigned short u16;
typedef __attribute__((ext_vector_type(8))) u16 u16x8;
typedef __attribute__((ext_vector_type(4))) u16 u16x4;
typedef __attribute__((ext_vector_type(8))) short s16x8;   // bf16x8 MFMA frag
typedef __attribute__((ext_vector_type(4))) float f32x4;

__device__ __forceinline__ u16 f2b(float f) {
  unsigned int x = __float_as_uint(f);
  return (u16)((x + 0x7fffu + ((x >> 16) & 1u)) >> 16);
}
__device__ __forceinline__ float b2f(u16 u) {
  return __uint_as_float(((unsigned int)u) << 16);
}
__device__ __forceinline__ f32x4 mfma16(s16x8 a, s16x8 b, f32x4 c) {
  return __builtin_amdgcn_mfma_f32_16x16x32_bf16(a, b, c, 0, 0, 0);
}

// ---------- dtype-flexible load/store (flag decided on device) ----------
__device__ __forceinline__ float ldsel(const void* p, int i, bool bf) {
  if (bf) return __bfloat162float(((const __hip_bfloat16*)p)[i]);
  return ((const float*)p)[i];
}
__device__ __forceinline__ void stsel(void* p, int i, float v, bool bf) {
  if (bf) ((__hip_bfloat16*)p)[i] = __float2bfloat16(v);
  else ((float*)p)[i] = v;
}

__global__ void detect_dtype_k(const void* x, float* flag) {
  __shared__ int sh[256];
  int tid = threadIdx.x;
  const __hip_bfloat16* xb = (const __hip_bfloat16*)x;
  int ok = 0;
  for (int i = tid; i < 1024; i += 256) {
    float v = fabsf(__bfloat162float(xb[2 * i]));
    if (v > 9.5e-7f && v < 1.05e6f) ok++;
  }
  sh[tid] = ok;
  __syncthreads();
  for (int s = 128; s > 0; s >>= 1) {
    if (tid < s) sh[tid] += sh[tid + s];
    __syncthreads();
  }
  if (tid == 0) flag[0] = (sh[0] > 512) ? 1.f : 0.f;
}

// ---------- pack 1x1 weights -> bf16 [O*Cin] (k-contiguous, coalesced) ----------
__global__ __launch_bounds__(256)
void pack_w_k(const void* __restrict__ src, u16* __restrict__ dst,
              int OCin, const float* __restrict__ dflag) {
  bool bf = dflag[0] > 0.5f;
  int gid = blockIdx.x * 256 + threadIdx.x;
  if (gid >= OCin) return;
  dst[gid] = f2b(ldsel(src, gid, bf));
}

// ---------- pack 3x3 weights (O,Ci,3,3) -> bf16 [t][O][Cin] ----------
// thread owns one (o,ci): 9 contiguous reads (one line), 9 coalesced stores.
__global__ __launch_bounds__(256)
void pack9_w_k(const void* __restrict__ src, u16* __restrict__ dst,
               int OCin, const float* __restrict__ dflag) {
  bool bf = dflag[0] > 0.5f;
  int gid = blockIdx.x * 256 + threadIdx.x;
  if (gid >= OCin) return;
  #pragma unroll
  for (int t = 0; t < 9; ++t)
    dst[(size_t)t * OCin + gid] = f2b(ldsel(src, gid * 9 + t, bf));
}

// ---------- depthwise 3x3 conv (ALPF stage A) -> bf16 [C][HW] ----------
__global__ __launch_bounds__(256)
void dwconv_k(const void* x, const void* wt, const void* bs, u16* y,
              const float* dflag) {
  bool bf = dflag[0] > 0.5f;
  int gid = blockIdx.x * 256 + threadIdx.x;           // 802816 exact
  int c = gid / HWP, p = gid - c * HWP;
  int h = p / WWC, w = p - h * WWC;
  float acc = ldsel(bs, c, bf);
  #pragma unroll
  for (int t = 0; t < 9; ++t) {
    int dh = t / 3 - 1, dw = t % 3 - 1;
    int hh = h + dh, ww = w + dw;
    if (hh >= 0 && hh < HH && ww >= 0 && ww < WWC)
      acc += ldsel(x, c * HWP + hh * WWC + ww, bf) * ldsel(wt, c * 9 + t, bf);
  }
  y[gid] = f2b(acc);
}

// ---------- MFMA GEMM / conv-as-GEMM, 32x32 tile (all GEMM sites) ----------
// OMODE 0: fp32 Y[o][p]; 1: flag-dtype Y[o][p]; 2: bf16 Y[p][o]; 3: bf16 Y[o][p].
// xmode  0: fp32 X[Cin][HW]; 1: flag X[Cin][HW]; 2: bf16 X[p][Cin]; 3: bf16 X[Cin][HW].
// ADDIN: bf16 [o][HW]. bid swizzle: o0 = bid % NO -> per-XCD weight locality.
template<int TAPS, int ACT, bool ADDIN, int OMODE>
__global__ __launch_bounds__(256)
void mgemm32_k(const u16* __restrict__ Wp, const void* __restrict__ X,
               const void* __restrict__ bias, const u16* __restrict__ addin,
               void* __restrict__ Y, int Cin,
               const float* __restrict__ dflag, int xmode, int bias_off) {
  bool wbf = dflag[0] > 0.5f;
  bool xbf = (xmode == 1) ? wbf : false;
  __shared__ u16 Ws[32][72];   // [o][k]
  __shared__ u16 Xs[32][72];   // [p][k]
  int NO = gridDim.y;
  int O = NO * 32;
  int bid = blockIdx.x + blockIdx.y * gridDim.x;
  int p0 = (bid / NO) * 32, o0 = (bid % NO) * 32;
  int tid = threadIdx.x, lane = tid & 63, wv = tid >> 6;
  int oq = (wv & 1) * 16, pq = (wv >> 1) * 16;
  int frow = lane & 15, kgrp = (lane >> 4) * 8;
  int wol = tid >> 3, wkk = (tid & 7) * 8;       // W: 32 rows x 64 k
  int pl = tid & 31, xkk = (tid >> 5) * 8;       // X: 32 rows x 64 k
  int p = p0 + pl, h = p / WWC, w = p - h * WWC;
  f32x4 acc = {0.f, 0.f, 0.f, 0.f};
  for (int t = 0; t < TAPS; ++t) {
    int dh = t / 3 - 1, dw = t % 3 - 1;
    int hh = h + dh, ww = w + dw;
    bool rowok = (TAPS == 1) || ((hh >= 0) && (hh < HH) && (ww >= 0) && (ww < WWC));
    int xoff = (TAPS == 1) ? p : hh * WWC + ww;
    const u16* Wrow = Wp + (size_t)t * O * Cin;
    for (int kb = 0; kb < Cin; kb += 64) {
      __syncthreads();
      *(u16x8*)&Ws[wol][wkk] =
          *(const u16x8*)&Wrow[(size_t)(o0 + wol) * Cin + kb + wkk];
      {
        u16x8 xv;
        if (xmode == 2) {
          if (rowok) {
            xv = *(const u16x8*)&((const u16*)X)[(size_t)xoff * Cin + kb + xkk];
          } else {
            #pragma unroll
            for (int j = 0; j < 8; ++j) xv[j] = 0;
          }
        } else if (xmode == 3) {
          #pragma unroll
          for (int j = 0; j < 8; ++j)
            xv[j] = rowok ? ((const u16*)X)[(size_t)(kb + xkk + j) * HWP + xoff]
                          : (u16)0;
        } else {
          #pragma unroll
          for (int j = 0; j < 8; ++j) {
            int kk = xkk + j;
            float v = rowok ? ldsel(X, (size_t)(kb + kk) * HWP + xoff, xbf) : 0.f;
            xv[j] = f2b(v);
          }
        }
        *(u16x8*)&Xs[pl][xkk] = xv;
      }
      __syncthreads();
      #pragma unroll
      for (int ks = 0; ks < 2; ++ks) {
        s16x8 aw = *(const s16x8*)&Ws[oq + frow][ks * 32 + kgrp];
        s16x8 ax = *(const s16x8*)&Xs[pq + frow][ks * 32 + kgrp];
        acc = mfma16(aw, ax, acc);
      }
    }
  }
  // D mapping (verified): col = lane&15 -> p, row = (lane>>4)*4+r -> o
  int orow = (lane >> 4) * 4;
  int ogb = o0 + oq + orow;
  int pg = p0 + pq + frow;
  if (OMODE == 2) {
    u16x4 st;
    #pragma unroll
    for (int r = 0; r < 4; ++r) {
      float yv = acc[r] + ldsel(bias, bias_off + ogb + r, wbf);
      if (ACT == 1) yv = (yv >= 0.f) ? yv : 0.2f * yv;
      if (ADDIN) yv += b2f(addin[(size_t)(ogb + r) * HWP + pg]);
      st[r] = f2b(yv);
    }
    *(u16x4*)&((u16*)Y)[(size_t)pg * O + ogb] = st;
  } else {
    #pragma unroll
    for (int r = 0; r < 4; ++r) {
      int og = ogb + r;
      float yv = acc[r] + ldsel(bias, bias_off + og, wbf);
      if (ACT == 1) yv = (yv >= 0.f) ? yv : 0.2f * yv;
      if (ADDIN) yv += b2f(addin[(size_t)og * HWP + pg]);
      if (OMODE == 3) ((u16*)Y)[(size_t)og * HWP + pg] = f2b(yv);
      else stsel(Y, (size_t)og * HWP + pg, yv, (OMODE == 1) && wbf);
    }
  }
}

// ---------- 1x1 conv 128 -> 9 + softmax (bf16 hid in, bf16 out) ----------
template<bool DELTA>
__global__ __launch_bounds__(256)
void pw9_v2_k(const void* __restrict__ w2, const void* __restrict__ b2,
              const u16* __restrict__ hid, u16* __restrict__ out9,
              const float* __restrict__ dflag) {
  bool bf = dflag[0] > 0.5f;
  __shared__ float Wl[9][128];
  __shared__ float Pl[4][9][33];
  int tid = threadIdx.x;
  for (int i = tid; i < 1152; i += 256) Wl[i >> 7][i & 127] = ldsel(w2, i, bf);
  __syncthreads();
  int pix = tid & 31, cig = tid >> 5;        // 8 groups x 16 ci
  int p = blockIdx.x * 32 + pix;
  int ci0 = cig * 16;
  float acc[9] = {0.f, 0.f, 0.f, 0.f, 0.f, 0.f, 0.f, 0.f, 0.f};
  #pragma unroll
  for (int j = 0; j < 16; ++j) {
    float xv = b2f(hid[(size_t)(ci0 + j) * HWP + p]);
    #pragma unroll
    for (int t = 0; t < 9; ++t) acc[t] += Wl[t][ci0 + j] * xv;
  }
  #pragma unroll
  for (int t = 0; t < 9; ++t) acc[t] += __shfl_xor(acc[t], 32);
  int wv = tid >> 6;
  if ((tid & 63) < 32) {
    #pragma unroll
    for (int t = 0; t < 9; ++t) Pl[wv][t][pix] = acc[t];
  }
  __syncthreads();
  if (tid < 32) {
    float a[9];
    #pragma unroll
    for (int t = 0; t < 9; ++t)
      a[t] = Pl[0][t][pix] + Pl[1][t][pix] + Pl[2][t][pix] + Pl[3][t][pix] +
             ldsel(b2, t, bf);
    float mx = a[0];
    #pragma unroll
    for (int t = 1; t < 9; ++t) mx = fmaxf(mx, a[t]);
    float s = 0.f;
    #pragma unroll
    for (int t = 0; t < 9; ++t) { a[t] = __expf(a[t] - mx); s += a[t]; }
    float inv = 1.f / s;
    #pragma unroll
    for (int t = 0; t < 9; ++t) {
      float v = a[t] * inv;
      if (DELTA) v = ((t == 4) ? 1.f : 0.f) - v;
      out9[(size_t)t * HWP + p] = f2b(v);
    }
  }
}

// ---------- spatially-varying 3x3 filter (bf16 w9, bf16 out) ----------
template<bool HIGH>
__global__ __launch_bounds__(256)
void spatial_filter_k(const void* x, const u16* __restrict__ w9,
                      u16* __restrict__ y, const float* dflag) {
  bool bf = dflag[0] > 0.5f;
  int gid = blockIdx.x * 256 + threadIdx.x;
  int c = gid / HWP, p = gid - c * HWP;
  int h = p / WWC, w = p - h * WWC;
  float acc = HIGH ? ldsel(x, gid, bf) : 0.f;
  #pragma unroll
  for (int t = 0; t < 9; ++t) {
    int dh = t / 3 - 1, dw = t % 3 - 1;
    int hh = h + dh, ww = w + dw;
    if (hh >= 0 && hh < HH && ww >= 0 && ww < WWC)
      acc += ldsel(x, c * HWP + hh * WWC + ww, bf) * b2f(w9[t * HWP + p]);
  }
  y[gid] = f2b(acc);
}

// ---------- flash attention partial (R12 version, unchanged control) ----------
__global__ __launch_bounds__(256)
void attn_part_k(const u16* __restrict__ Qb, const u16* __restrict__ Kb,
                 const u16* __restrict__ Vb, u16* __restrict__ Op,
                 float* __restrict__ Lb) {
  __shared__ u16 Qs[64][40];
  __shared__ u16 Ks[64][40];
  __shared__ u16 Vs[32][72];      // [d][m] linear
  __shared__ u16 Ps[4][16][72];   // per-wave P tile [q][m]
  int h = blockIdx.y, n0 = blockIdx.x * 64, sz = blockIdx.z;
  int tid = threadIdx.x, lane = tid & 63, wv = tid >> 6;
  int frow = lane & 15, kgrp = (lane >> 4) * 8, gq = lane >> 4;
  int ml = tid >> 2, dseg = (tid & 3) * 8;     // K staging: [64 m][32 d]
  int vd = tid >> 3, vm = (tid & 7) * 8;       // V staging: [32 d][64 m]
  const float QS = 0.17677669529663687f * 1.4426950408889634f;  // scale*log2e
  {
    u16x8 qv = *(const u16x8*)&Qb[(size_t)(n0 + ml) * 256 + h * 32 + dseg];
    #pragma unroll
    for (int j = 0; j < 8; ++j) qv[j] = f2b(b2f(qv[j]) * QS);
    *(u16x8*)&Qs[ml][dseg] = qv;
  }
  __syncthreads();
  s16x8 aq = *(const s16x8*)&Qs[wv * 16 + frow][kgrp];
  f32x4 oa0 = {0.f, 0.f, 0.f, 0.f}, oa1 = {0.f, 0.f, 0.f, 0.f};
  float lsum = 0.f;
  int t_begin = (49 * sz) / NSPLIT, t_end = (49 * (sz + 1)) / NSPLIT;
  u16x8 kreg = *(const u16x8*)&Kb[(size_t)(t_begin * 64 + ml) * 256 + h * 32 + dseg];
  u16x8 vreg = *(const u16x8*)&Vb[(size_t)(h * 32 + vd) * HWP + t_begin * 64 + vm];
  for (int t = t_begin; t < t_end; ++t) {
    __syncthreads();
    *(u16x8*)&Ks[ml][dseg] = kreg;
    *(u16x8*)&Vs[vd][vm] = vreg;
    if (t + 1 < t_end) {
      kreg = *(const u16x8*)&Kb[(size_t)((t + 1) * 64 + ml) * 256 + h * 32 + dseg];
      vreg = *(const u16x8*)&Vb[(size_t)(h * 32 + vd) * HWP + (t + 1) * 64 + vm];
    }
    __syncthreads();
    f32x4 zero = {0.f, 0.f, 0.f, 0.f};
    #pragma unroll
    for (int fm = 0; fm < 4; ++fm) {
      s16x8 ak = *(const s16x8*)&Ks[fm * 16 + frow][kgrp];
      f32x4 s = mfma16(ak, aq, zero);       // D[m][q]: rows=m, col=q=frow
      u16x4 pe;
      #pragma unroll
      for (int r = 0; r < 4; ++r) {
        float e = exp2f(fminf(s[r], 43.f));
        lsum += e;
        pe[r] = (u16)(__float_as_uint(e) >> 16);  // trunc-to-bf16 (P in (0,1])
      }
      *(u16x4*)&Ps[wv][frow][fm * 16 + gq * 4] = pe;
    }
    #pragma unroll
    for (int ks = 0; ks < 2; ++ks) {
      s16x8 ap = *(const s16x8*)&Ps[wv][frow][ks * 32 + kgrp];
      s16x8 bv0 = *(const s16x8*)&Vs[frow][ks * 32 + kgrp];
      s16x8 bv1 = *(const s16x8*)&Vs[16 + frow][ks * 32 + kgrp];
      oa0 = mfma16(ap, bv0, oa0);
      oa1 = mfma16(ap, bv1, oa1);
    }
  }
  lsum += __shfl_xor(lsum, 16);
  lsum += __shfl_xor(lsum, 32);
  if (lane < 16)
    Lb[(size_t)(sz * 8 + h) * HWP + n0 + wv * 16 + frow] = lsum;
  #pragma unroll
  for (int r = 0; r < 4; ++r) {
    int n = n0 + wv * 16 + gq * 4 + r;
    Op[(size_t)(sz * 256 + h * 32 + frow) * HWP + n]      = f2b(oa0[r]);
    Op[(size_t)(sz * 256 + h * 32 + 16 + frow) * HWP + n] = f2b(oa1[r]);
  }
}

// ---------- combine NSPLIT attention partials -> bf16 [C][HW] ----------
__global__ __launch_bounds__(256)
void attn_combine_k(const u16* __restrict__ Op, const float* __restrict__ Lb,
                    u16* __restrict__ A) {
  int gid = blockIdx.x * 256 + threadIdx.x;   // 802816
  int n = gid % HWP, hd = gid / HWP, h = hd >> 5;
  float L = 0.f, O = 0.f;
  #pragma unroll
  for (int s = 0; s < NSPLIT; ++s) {
    L += Lb[(size_t)(s * 8 + h) * HWP + n];
    O += b2f(Op[(size_t)(s * 256 + hd) * HWP + n]);
  }
  A[(size_t)hd * HWP + n] = f2b(O / L);
}

extern "C" void kernel_launch(void* const* d_in, const int* in_sizes, int n_in,
                              void* d_out, int out_size, void* d_ws, size_t ws_size,
                              hipStream_t stream) {
  const void* dec   = d_in[0];
  const void* enc   = d_in[1];
  const void* dw_w  = d_in[2];
  const void* dw_b  = d_in[3];
  const void* p1_w  = d_in[4];
  const void* p1_b  = d_in[5];
  const void* p2_w  = d_in[6];
  const void* p2_b  = d_in[7];
  const void* c1_w  = d_in[8];
  const void* c1_b  = d_in[9];
  const void* c2_w  = d_in[10];
  const void* c2_b  = d_in[11];
  const void* q_w   = d_in[12];
  const void* q_b   = d_in[13];
  const void* kv_w  = d_in[14];
  const void* kv_b  = d_in[15];
  const void* out_w = d_in[16];
  const void* out_b = d_in[17];
  const void* fu_w  = d_in[18];
  const void* fu_b  = d_in[19];

  const int CH = CC * HWP;     // 802816
  float* flag = (float*)d_ws;                       // 8 floats
  u16* pk     = (u16*)(flag + 8);
  u16* A      = pk;              pk += CH;            // dwconv out / attn out, bf16 [C][HW]
  u16* hid    = pk;              pk += 128 * HWP;     // bf16 [128][HW]
  u16* s9     = pk;              pk += 9 * HWP;       // bf16 [9][HW]
  u16* Bb     = pk;              pk += CH;            // f_smooth / f_high, bf16 [C][HW]
  u16* qb16   = pk;              pk += CH;            // q bf16 [n][256]; later fused_in [p][256]
  u16* k16    = pk;              pk += CH;            // K bf16 [m][256]
  u16* v16    = pk;              pk += CH;            // V bf16 [d][HWP]
  u16* wp_p1  = pk;              pk += 128 * 256;
  u16* wp_q   = pk;              pk += 256 * 256;
  u16* wp_kv  = pk;              pk += 512 * 256;
  u16* wp_out = pk;              pk += 256 * 256;
  u16* wp_c1  = pk;              pk += 128 * 256 * 9;
  u16* wp_fu  = pk;              pk += 256 * 256 * 9;
  pk += (size_t)(-(intptr_t)pk) & 7;                  // align to 4 floats
  float* Lb   = (float*)pk;                           // 32*HWP f32
  u16* Opart  = (u16*)(Lb + 32 * HWP);                // 1024*HWP u16

  dim3 blk(256);
  detect_dtype_k<<<1, blk, 0, stream>>>(dec, flag);

  // ---- pack weights to bf16 k-contiguous ----
  pack_w_k<<<128, blk, 0, stream>>>(p1_w, wp_p1, 128 * 256, flag);
  pack_w_k<<<256, blk, 0, stream>>>(q_w, wp_q, 256 * 256, flag);
  pack_w_k<<<512, blk, 0, stream>>>(kv_w, wp_kv, 512 * 256, flag);
  pack_w_k<<<256, blk, 0, stream>>>(out_w, wp_out, 256 * 256, flag);
  pack9_w_k<<<128, blk, 0, stream>>>(c1_w, wp_c1, 128 * 256, flag);
  pack9_w_k<<<256, blk, 0, stream>>>(fu_w, wp_fu, 256 * 256, flag);

  // ---- ALPF: kw = softmax(p2(lrelu(p1(dw(dec))))) ----
  dwconv_k<<<3136, blk, 0, stream>>>(dec, dw_w, dw_b, A, flag);
  mgemm32_k<1, 1, false, 3><<<dim3(98, 4), blk, 0, stream>>>(
      wp_p1, A, p1_b, nullptr, hid, 256, flag, 3, 0);
  pw9_v2_k<false><<<98, blk, 0, stream>>>(p2_w, p2_b, hid, s9, flag);
  spatial_filter_k<false><<<3136, blk, 0, stream>>>(dec, s9, Bb, flag);

  // ---- q / k / v projections ----
  mgemm32_k<1, 0, false, 2><<<dim3(98, 8), blk, 0, stream>>>(
      wp_q, Bb, q_b, nullptr, qb16, 256, flag, 3, 0);
  mgemm32_k<1, 0, false, 2><<<dim3(98, 8), blk, 0, stream>>>(
      wp_kv, enc, kv_b, nullptr, k16, 256, flag, 1, 0);
  mgemm32_k<1, 0, false, 3><<<dim3(98, 8), blk, 0, stream>>>(
      wp_kv + 256 * 256, enc, kv_b, nullptr, v16, 256, flag, 1, 256);

  // ---- attention: 4-way KV-split partials + combine ----
  attn_part_k<<<dim3(49, 8, NSPLIT), blk, 0, stream>>>(qb16, k16, v16, Opart, Lb);
  attn_combine_k<<<3136, blk, 0, stream>>>(Opart, Lb, A);

  // ---- AHPF: whp = delta - softmax(c2(lrelu(c1(enc)))) ----
  mgemm32_k<9, 1, false, 3><<<dim3(98, 4), blk, 0, stream>>>(
      wp_c1, enc, c1_b, nullptr, hid, 256, flag, 1, 0);
  pw9_v2_k<true><<<98, blk, 0, stream>>>(c2_w, c2_b, hid, s9, flag);
  spatial_filter_k<true><<<3136, blk, 0, stream>>>(enc, s9, Bb, flag);

  // ---- out proj + f_high add -> bf16 [p][256] (reuses qb16, q is dead) ----
  mgemm32_k<1, 0, true, 2><<<dim3(98, 8), blk, 0, stream>>>(
      wp_out, A, out_b, Bb, qb16, 256, flag, 3, 0);

  // ---- fusion 3x3 conv (bf16 pixel-major X) -> d_out ----
  mgemm32_k<9, 0, false, 1><<<dim3(98, 8), blk, 0, stream>>>(
      wp_fu, qb16, fu_b, nullptr, d_out, 256, flag, 2, 0);
}